// Round 16
// baseline (967.838 us; speedup 1.0000x reference)
//
#include <hip/hip_runtime.h>
#include <math.h>

#define NXG 512
#define NPTS (NXG * NXG)
#define NB 4
#define NT 256
#define NM 256
#define K 16                // steps per chunk (8 double-steps)
#define NCH (NT / K)        // 16 chunks
#define WROWS 128           // window rows (64 interior + 2*32 halo)
#define WCOLS 128           // window cols
#define NTHR 512            // 16 row-groups x 32 col-threads; 8x4 own cells
#define NTILES 64           // 8x8 tiles (64x64 interior)
#define LROWS 136           // LDS slots: window row + 4 (rows -4..131)

// ---------------------------------------------------------------------------
__global__ __launch_bounds__(256) void zero_kernel(float4* __restrict__ p) {
    p[blockIdx.x * 256 + threadIdx.x] = make_float4(0.f, 0.f, 0.f, 0.f);
}

// One-time vel2/12 table in field layout.
__global__ __launch_bounds__(256) void vel2_kernel(const float* __restrict__ x,
                                                   float* __restrict__ vel2) {
    int gid = blockIdx.x * 256 + threadIdx.x;
    int b = gid >> 18;
    int idx = gid & (NPTS - 1);
    int i = idx >> 9, j = idx & 511;
    float v;
    if (i < 55 || i >= 457 || j < 55 || j >= 457) v = 1e-6f;
    else if (i >= 128 && i < 384 && j >= 128 && j < 384)
        v = x[(b << 16) | ((i - 128) << 8) | (j - 128)];
    else v = 1.5f;
    float a = (2e-05f * v) / 1e-04f;
    vel2[gid] = a * a * (1.0f / 12.0f);
}

// Wave shifts. Junk enters only at column-edge threads (window cols 0-3 /
// 124-127) — garbage-tolerant by the 32-wide halo argument.
__device__ __forceinline__ float dpp_left(float v) {   // lane-1
    return __int_as_float(__builtin_amdgcn_mov_dpp(__float_as_int(v),
                                                   0x138, 0xf, 0xf, true));
}
__device__ __forceinline__ float dpp_right(float v) {  // lane+1
    return __int_as_float(__builtin_amdgcn_mov_dpp(__float_as_int(v),
                                                   0x130, 0xf, 0xf, true));
}

// ---------------------------------------------------------------------------
// One row update, IN PLACE: dst holds the t-1 field row, gets the t+1 row.
// ctr/xm*/xp* are the t-field rows; v2 is vel^2/12.
// ---------------------------------------------------------------------------
__device__ __forceinline__ void upd_row(
    const float* __restrict__ xm2, const float* __restrict__ xm1,
    const float* __restrict__ ctr,
    const float* __restrict__ xp1, const float* __restrict__ xp2,
    const float* __restrict__ v2, float* __restrict__ dst)
{
    float y[8] = {dpp_left(ctr[2]), dpp_left(ctr[3]),
                  ctr[0], ctr[1], ctr[2], ctr[3],
                  dpp_right(ctr[0]), dpp_right(ctr[1])};
#pragma unroll
    for (int c = 0; c < 4; ++c) {
        float cc = ctr[c];
        float sum1 = (xm1[c] + xp1[c]) + (y[c + 1] + y[c + 3]);
        float sum2 = (xm2[c] + xp2[c]) + (y[c] + y[c + 4]);
        float w = fmaf(-60.0f, cc, fmaf(16.0f, sum1, -sum2));
        dst[c] = fmaf(v2[c], w, fmaf(2.0f, cc, -dst[c]));
    }
}

// ---------------------------------------------------------------------------
// Chunk kernel: 8 double-steps, ONE barrier per 2 time steps.
// C[16][4] = f_n rows r0-4..r0+11; P[12][4] = f_{n-1} rows r0-2..r0+9;
// V[12][4] = vel2/12 rows r0-2..r0+9.
// Step A: P <- f_{n+1} on 12 rows (registers only, redundant halo rows are
// bit-exact vs neighbors). Step B: C own 8 rows <- f_{n+2}. Publish own 8
// rows, barrier, refill C's 8 halo rows from the ping-pong LDS buffer.
// ---------------------------------------------------------------------------
__global__ __launch_bounds__(NTHR, 2) void chunk_kernel(
    const float* __restrict__ se,      // (64,)
    float* __restrict__ out,           // (4,1,256,256) = [b][m][t]
    const float* __restrict__ gA,      // f_{n0}
    const float* __restrict__ gB,      // f_{n0-1}
    float* __restrict__ wA,            // f_{n0+K}
    float* __restrict__ wB,            // f_{n0+K-1}
    const float* __restrict__ vel2,    // v2/12 table, field layout
    const int4* __restrict__ thrTab,   // NTILES x NTHR
    const float* __restrict__ srcT,
    int n0)
{
    __shared__ __align__(16) float L0[LROWS * WCOLS];
    __shared__ __align__(16) float L1[LROWS * WCOLS];

    const int tid = threadIdx.x;
    const int blk = blockIdx.x;
    const int b   = blk >> 6;          // batch
    const int tb  = blk & 63;          // tile
    const int gi0 = (tb >> 3) << 6;
    const int gj0 = (tb & 7) << 6;
    const int bi0 = gi0 - 32;
    const int bj0 = gj0 - 32;

    const int grp = tid >> 5;          // 0..15
    const int r0  = grp << 3;          // own window rows r0..r0+7
    const int c0  = (tid & 31) << 2;   // own window cols

    // ---- zero the 4+4 pad slots (rows -4..-1, 128..131) of both buffers ----
    {
        int buf = tid >= 256;
        int q = tid & 255;             // 0..255
        int pr = q >> 5;               // 0..7
        int pc = (q & 31) << 2;
        int slot = (pr < 4) ? pr : (pr + 128);   // 0..3, 132..135
        float* S = buf ? L1 : L0;
        *(float4*)&S[slot * WCOLS + pc] = make_float4(0.f, 0.f, 0.f, 0.f);
    }

    // ---- prologue: C (16 rows f_{n0}), P (12 rows f_{n0-1}), V (12 rows) ----
    float C[16][4], P[12][4], V[12][4];
    const float* gAb = gA + (b << 18);
    const float* gBb = gB + (b << 18);
    const float* gVb = vel2 + (b << 18);
#pragma unroll
    for (int r = 0; r < 16; ++r) {
        int gi = (bi0 + r0 - 4 + r) & 511;
        int gj = (bj0 + c0) & 511;
        float4 t = *(const float4*)&gAb[(gi << 9) | gj];
        C[r][0] = t.x; C[r][1] = t.y; C[r][2] = t.z; C[r][3] = t.w;
    }
#pragma unroll
    for (int r = 0; r < 12; ++r) {
        int gi = (bi0 + r0 - 2 + r) & 511;
        int gj = (bj0 + c0) & 511;
        float4 p = *(const float4*)&gBb[(gi << 9) | gj];
        float4 v = *(const float4*)&gVb[(gi << 9) | gj];
        P[r][0] = p.x; P[r][1] = p.y; P[r][2] = p.z; P[r][3] = p.w;
        V[r][0] = v.x; V[r][1] = v.y; V[r][2] = v.z; V[r][3] = v.w;
    }

    // ---- inj/meas descriptors ----
    // x: injA (-1 / seIdx<<8 | cell6) over the EXTENDED 12-row P range
    // y: injB (-1 / seIdx<<8 | cell5) over own 8 rows
    // z,w: meas (0 / 0x8000 | cell5<<8 | m) over own 8 rows
    const int4 tw = thrTab[(tb << 9) | tid];
    float injVA = 0.0f, injVB = 0.0f;
    if (tw.x >= 0) injVA = 0.09f * se[tw.x >> 8];
    if (tw.y >= 0) injVB = 0.09f * se[tw.y >> 8];
    const int cellA = tw.x & 63;   // P index: pr<<2|c
    const int cellB = tw.y & 31;   // own-row index: br<<2|c
    int m1Cell = -1, m1Addr = 0, m2Cell = -1, m2Addr = 0;
    if (tw.z != 0) { m1Cell = (tw.z >> 8) & 31; m1Addr = (b << 16) | ((tw.z & 255) << 8); }
    if (tw.w != 0) { m2Cell = (tw.w >> 8) & 31; m2Addr = (b << 16) | ((tw.w & 255) << 8); }
    const bool rareA = (tw.x >= 0) || (m1Cell >= 0) || (m2Cell >= 0);
    const bool rareB = (tw.y >= 0) || (m1Cell >= 0) || (m2Cell >= 0);

#pragma unroll 1
    for (int i = 0; i < K / 2; ++i) {
        const int n = n0 + 2 * i;

        // ---- step A: P <- f_{n+1} on rows r0-2..r0+9 (register-only) ----
#pragma unroll
        for (int pr = 0; pr < 12; ++pr)
            upd_row(C[pr], C[pr + 1], C[pr + 2], C[pr + 3], C[pr + 4],
                    V[pr], P[pr]);
        if (rareA) {
            if (tw.x >= 0) {
                float add = injVA * srcT[n];
#pragma unroll
                for (int pr = 0; pr < 12; ++pr)
#pragma unroll
                    for (int c = 0; c < 4; ++c)
                        if (((pr << 2) | c) == cellA) P[pr][c] += add;
            }
            if (m1Cell >= 0) {
                float v = 0.0f;
#pragma unroll
                for (int r = 0; r < 8; ++r)
#pragma unroll
                    for (int c = 0; c < 4; ++c)
                        if (((r << 2) | c) == m1Cell) v = P[r + 2][c];
                out[m1Addr | n] = v;
            }
            if (m2Cell >= 0) {
                float v = 0.0f;
#pragma unroll
                for (int r = 0; r < 8; ++r)
#pragma unroll
                    for (int c = 0; c < 4; ++c)
                        if (((r << 2) | c) == m2Cell) v = P[r + 2][c];
                out[m2Addr | n] = v;
            }
        }

        // ---- step B: C own rows <- f_{n+2} ----
#pragma unroll
        for (int br = 0; br < 8; ++br)
            upd_row(P[br], P[br + 1], P[br + 2], P[br + 3], P[br + 4],
                    V[br + 2], C[br + 4]);
        if (rareB) {
            if (tw.y >= 0) {
                float add = injVB * srcT[n + 1];
#pragma unroll
                for (int r = 0; r < 8; ++r)
#pragma unroll
                    for (int c = 0; c < 4; ++c)
                        if (((r << 2) | c) == cellB) C[r + 4][c] += add;
            }
            if (m1Cell >= 0) {
                float v = 0.0f;
#pragma unroll
                for (int r = 0; r < 8; ++r)
#pragma unroll
                    for (int c = 0; c < 4; ++c)
                        if (((r << 2) | c) == m1Cell) v = C[r + 4][c];
                out[m1Addr | (n + 1)] = v;
            }
            if (m2Cell >= 0) {
                float v = 0.0f;
#pragma unroll
                for (int r = 0; r < 8; ++r)
#pragma unroll
                    for (int c = 0; c < 4; ++c)
                        if (((r << 2) | c) == m2Cell) v = C[r + 4][c];
                out[m2Addr | (n + 1)] = v;
            }
        }

        // ---- publish own 8 rows of f_{n+2}; ONE barrier; refill C halo ----
        if (i < K / 2 - 1) {
            float* Lw = (i & 1) ? L1 : L0;
#pragma unroll
            for (int r = 0; r < 8; ++r)
                *(float4*)&Lw[(r0 + 4 + r) * WCOLS + c0] =
                    make_float4(C[r + 4][0], C[r + 4][1], C[r + 4][2], C[r + 4][3]);
            __syncthreads();
#pragma unroll
            for (int r = 0; r < 4; ++r) {
                float4 u = *(const float4*)&Lw[(r0 + r) * WCOLS + c0];       // rows r0-4..r0-1
                float4 d = *(const float4*)&Lw[(r0 + 12 + r) * WCOLS + c0]; // rows r0+8..r0+11
                C[r][0] = u.x; C[r][1] = u.y; C[r][2] = u.z; C[r][3] = u.w;
                C[12 + r][0] = d.x; C[12 + r][1] = d.y; C[12 + r][2] = d.z; C[12 + r][3] = d.w;
            }
        }
    }

    // ---- write back interior: C own = f_{n0+K}, P own = f_{n0+K-1} ----
    if (r0 >= 32 && r0 < 96 && c0 >= 32 && c0 < 96) {
        int gj = gj0 + (c0 - 32);
#pragma unroll
        for (int r = 0; r < 8; ++r) {
            int gi = gi0 + (r0 - 32) + r;
            *(float4*)&wA[(b << 18) | (gi << 9) | gj] =
                make_float4(C[r + 4][0], C[r + 4][1], C[r + 4][2], C[r + 4][3]);
            *(float4*)&wB[(b << 18) | (gi << 9) | gj] =
                make_float4(P[r + 2][0], P[r + 2][1], P[r + 2][2], P[r + 2][3]);
        }
    }
}

// ---------------------------------------------------------------------------
extern "C" void kernel_launch(void* const* d_in, const int* in_sizes, int n_in,
                              void* d_out, int out_size, void* d_ws, size_t ws_size,
                              hipStream_t stream) {
    const float* x  = (const float*)d_in[0];
    const float* se = (const float*)d_in[1];
    float* out = (float*)d_out;

    float* ws = (float*)d_ws;
    const int FSZ = NB * NPTS;                 // 4 MB per field (floats)
    float* f[4]  = {ws, ws + FSZ, ws + 2 * FSZ, ws + 3 * FSZ};
    float* dVel  = ws + 4 * FSZ;                        // 4 MB
    int4*  dTT   = (int4*)(ws + 5 * FSZ);               // 64*512 int4 = 512KB
    float* dSrc  = (float*)(ws + 5 * FSZ + NTILES * NTHR * 4);

    static int   h_t4[NTILES * NTHR * 4];
    static float h_src[NT];
    static int   h_mx[NM], h_my[NM];
    for (int m = 0; m < NM; ++m) {
        double theta = (2.0 * M_PI * (double)m) / 256.0;
        h_mx[m] = (int)(256.0 + 200.0 * cos(theta));
        h_my[m] = (int)(256.0 + 200.0 * sin(theta));
    }
    for (int i = 0; i < NTILES * NTHR; ++i) {
        h_t4[4 * i] = -1; h_t4[4 * i + 1] = -1;
        h_t4[4 * i + 2] = 0; h_t4[4 * i + 3] = 0;
    }
    for (int tile = 0; tile < NTILES; ++tile) {
        int bi0 = ((tile >> 3) << 6) - 32;
        int bj0 = ((tile & 7) << 6) - 32;
        for (int m = 0; m < NM; ++m) {
            int d = (h_mx[m] - bi0) & 511;
            int e = (h_my[m] - bj0) & 511;
            if (e >= WCOLS || d >= WROWS) continue;
            int ct = e >> 2, c = e & 3;
            // own-row slot: injB + measurements
            {
                int g = d >> 3;
                int tidx = g * 32 + ct;
                int bidx = (tile * NTHR + tidx) * 4;
                int bcell = ((d & 7) << 2) | c;          // 0..31
                if ((m & 3) == 0) h_t4[bidx + 1] = ((m >> 2) << 8) | bcell;
                if (d >= 32 && d < 96 && e >= 32 && e < 96) {
                    int pk = 0x8000 | (bcell << 8) | m;
                    if (!(h_t4[bidx + 2] & 0x8000)) h_t4[bidx + 2] = pk;
                    else                            h_t4[bidx + 3] = pk;
                }
            }
            // extended A-range injection: all groups whose 12-row P window
            // covers row d (redundant copies must all inject)
            if ((m & 3) == 0) {
                for (int g = (d >> 3) - 1; g <= (d >> 3) + 1; ++g) {
                    if (g < 0 || g >= 16) continue;
                    int pr = d - 8 * g + 2;
                    if (pr < 0 || pr >= 12) continue;
                    int tidx = g * 32 + ct;
                    int bidx = (tile * NTHR + tidx) * 4;
                    h_t4[bidx] = ((m >> 2) << 8) | ((pr << 2) | c);  // 0..47
                }
            }
        }
    }
    for (int t = 0; t < NT; ++t) {
        float tj  = (float)t * 2e-05f;
        float arg = (float)(2.0 * M_PI * 500.0) * tj;
        float d   = tj - 0.002f;
        float e   = -(d * d) / (float)(2.0 * 0.001 * 0.001);
        h_src[t]  = sinf(arg) * expf(e);
    }
    hipMemcpyAsync(dTT,  h_t4,  sizeof(h_t4), hipMemcpyHostToDevice, stream);
    hipMemcpyAsync(dSrc, h_src, sizeof(h_src), hipMemcpyHostToDevice, stream);

    // zero chunk-0 input pair (f0A,f0B contiguous = 8 MB)
    zero_kernel<<<2048, 256, 0, stream>>>((float4*)ws);
    // one-time vel2/12 table
    vel2_kernel<<<NB * NPTS / 256, 256, 0, stream>>>(x, dVel);

    for (int c = 0; c < NCH; ++c) {
        int p = c & 1, q = p ^ 1;
        chunk_kernel<<<NB * NTILES, NTHR, 0, stream>>>(
            se, out,
            f[2 * p], f[2 * p + 1],
            f[2 * q], f[2 * q + 1],
            dVel, dTT, dSrc, c * K);
    }
}

// Round 17
// 916.211 us; speedup vs baseline: 1.0563x; 1.0563x over previous
//
#include <hip/hip_runtime.h>
#include <math.h>

#define NXG 512
#define NPTS (NXG * NXG)
#define NB 4
#define NT 256
#define NM 256
#define K 8                 // steps per chunk
#define NCH (NT / K)        // 32 chunks
#define WR 96               // window rows (64 interior + 2*16 halo)
#define WC 64               // window cols (32 interior + 2*16 halo)
#define NTHR 192            // 12 row-groups x 16 col-threads; 8x4 cells
#define NTILES 128          // 8x16 tiles (64x32 interior) cover 512x512
#define LROWS 56            // LDS slots: (12+2 pad) groups x 4 boundary rows

// ---------------------------------------------------------------------------
__global__ __launch_bounds__(256) void zero_kernel(float4* __restrict__ p) {
    p[blockIdx.x * 256 + threadIdx.x] = make_float4(0.f, 0.f, 0.f, 0.f);
}

// One-time vel2/12 table in field layout.
__global__ __launch_bounds__(256) void vel2_kernel(const float* __restrict__ x,
                                                   float* __restrict__ vel2) {
    int gid = blockIdx.x * 256 + threadIdx.x;
    int b = gid >> 18;
    int idx = gid & (NPTS - 1);
    int i = idx >> 9, j = idx & 511;
    float v;
    if (i < 55 || i >= 457 || j < 55 || j >= 457) v = 1e-6f;
    else if (i >= 128 && i < 384 && j >= 128 && j < 384)
        v = x[(b << 16) | ((i - 128) << 8) | (j - 128)];
    else v = 1.5f;
    float a = (2e-05f * v) / 1e-04f;
    vel2[gid] = a * a * (1.0f / 12.0f);
}

// DPP wave shifts. Junk enters per-lane-group seams only into edge columns
// (window cols 0-3 / 60-63), which the 16-wide halo absorbs (validity
// shrinks 2 cols/step; interior [16,48) exact after 8 steps).
__device__ __forceinline__ float dpp_left(float v) {
    return __int_as_float(__builtin_amdgcn_mov_dpp(__float_as_int(v),
                                                   0x138, 0xf, 0xf, true));
}
__device__ __forceinline__ float dpp_right(float v) {
    return __int_as_float(__builtin_amdgcn_mov_dpp(__float_as_int(v),
                                                   0x130, 0xf, 0xf, true));
}

// ---------------------------------------------------------------------------
// One row: reads cur rows + old dst[r] (previous field), writes new field
// IN PLACE into dst[r]. No inj/meas in the hot path.
// ---------------------------------------------------------------------------
__device__ __forceinline__ void row_calc(
    const float (&cur)[8][4], float (&dst)[8][4],
    const float (&v2R)[8][4], int r,
    const float* __restrict__ xm2, const float* __restrict__ xm1,
    const float* __restrict__ xp1, const float* __restrict__ xp2)
{
    float y[8] = {dpp_left(cur[r][2]), dpp_left(cur[r][3]),
                  cur[r][0], cur[r][1], cur[r][2], cur[r][3],
                  dpp_right(cur[r][0]), dpp_right(cur[r][1])};
#pragma unroll
    for (int c = 0; c < 4; ++c) {
        float cc = cur[r][c];
        float sum1 = (xm1[c] + xp1[c]) + (y[c + 1] + y[c + 3]);
        float sum2 = (xm2[c] + xp2[c]) + (y[c] + y[c + 4]);
        float w = fmaf(-60.0f, cc, fmaf(16.0f, sum1, -sum2));
        dst[r][c] = fmaf(v2R[r][c], w, fmaf(2.0f, cc, -dst[r][c]));
    }
}

// ---------------------------------------------------------------------------
// One step: x-halo rows from LDS boundary slots; y-halo via DPP; halo-free
// rows 2..5 first; new field in place into nw; boundary rows 0,1,6,7 -> Ln.
// Slot map: group g owns slots (g+1)*4+{0..3} = its rows {0,1,6,7}.
// ---------------------------------------------------------------------------
__device__ __forceinline__ void do_step(
    const float* __restrict__ Lc, float* __restrict__ Ln,
    const float (&v2R)[8][4], float (&cur)[8][4], float (&nw)[8][4],
    int base, int c0)
{
    float4 a4 = *(const float4*)&Lc[(base - 2) * WC + c0];  // row r0-2
    float4 b4 = *(const float4*)&Lc[(base - 1) * WC + c0];  // row r0-1
    float4 c4 = *(const float4*)&Lc[(base + 4) * WC + c0];  // row r0+8
    float4 d4 = *(const float4*)&Lc[(base + 5) * WC + c0];  // row r0+9

#pragma unroll
    for (int r = 2; r < 6; ++r)
        row_calc(cur, nw, v2R, r, cur[r - 2], cur[r - 1], cur[r + 1], cur[r + 2]);

    float ha[4] = {a4.x, a4.y, a4.z, a4.w};
    float hb[4] = {b4.x, b4.y, b4.z, b4.w};
    row_calc(cur, nw, v2R, 0, ha, hb, cur[1], cur[2]);
    *(float4*)&Ln[(base + 0) * WC + c0] =
        make_float4(nw[0][0], nw[0][1], nw[0][2], nw[0][3]);
    row_calc(cur, nw, v2R, 1, hb, cur[0], cur[2], cur[3]);
    *(float4*)&Ln[(base + 1) * WC + c0] =
        make_float4(nw[1][0], nw[1][1], nw[1][2], nw[1][3]);

    float hc[4] = {c4.x, c4.y, c4.z, c4.w};
    float hd[4] = {d4.x, d4.y, d4.z, d4.w};
    row_calc(cur, nw, v2R, 6, cur[4], cur[5], cur[7], hc);
    *(float4*)&Ln[(base + 2) * WC + c0] =
        make_float4(nw[6][0], nw[6][1], nw[6][2], nw[6][3]);
    row_calc(cur, nw, v2R, 7, cur[5], cur[6], hc, hd);
    *(float4*)&Ln[(base + 3) * WC + c0] =
        make_float4(nw[7][0], nw[7][1], nw[7][2], nw[7][3]);
}

// ---------------------------------------------------------------------------
// Rare post-step patch: injection add (+ boundary-slot refresh), then
// measurement reads of the PATCHED new field.
// ---------------------------------------------------------------------------
__device__ __forceinline__ void patch_step(
    float (&f)[8][4], float* __restrict__ Ln, float* __restrict__ out,
    int base, int c0, int injCell, float addv,
    int m1Cell, int m1Addr, int m2Cell, int m2Addr, int n)
{
    if (injCell >= 0) {
#pragma unroll
        for (int r = 0; r < 8; ++r)
#pragma unroll
            for (int c = 0; c < 4; ++c)
                if (((r << 2) | c) == injCell) f[r][c] += addv;
        int ir = injCell >> 2;
        if (ir == 0) *(float4*)&Ln[(base + 0) * WC + c0] = make_float4(f[0][0], f[0][1], f[0][2], f[0][3]);
        if (ir == 1) *(float4*)&Ln[(base + 1) * WC + c0] = make_float4(f[1][0], f[1][1], f[1][2], f[1][3]);
        if (ir == 6) *(float4*)&Ln[(base + 2) * WC + c0] = make_float4(f[6][0], f[6][1], f[6][2], f[6][3]);
        if (ir == 7) *(float4*)&Ln[(base + 3) * WC + c0] = make_float4(f[7][0], f[7][1], f[7][2], f[7][3]);
    }
    if (m1Cell >= 0) {
        float v = 0.0f;
#pragma unroll
        for (int r = 0; r < 8; ++r)
#pragma unroll
            for (int c = 0; c < 4; ++c)
                if (((r << 2) | c) == m1Cell) v = f[r][c];
        out[m1Addr | n] = v;
    }
    if (m2Cell >= 0) {
        float v = 0.0f;
#pragma unroll
        for (int r = 0; r < 8; ++r)
#pragma unroll
            for (int c = 0; c < 4; ++c)
                if (((r << 2) | c) == m2Cell) v = f[r][c];
        out[m2Addr | n] = v;
    }
}

// ---------------------------------------------------------------------------
__global__ __launch_bounds__(NTHR, 2) void chunk_kernel(
    const float* __restrict__ se,
    float* __restrict__ out,
    const float* __restrict__ gA,      // f_{n0}
    const float* __restrict__ gB,      // f_{n0-1}
    float* __restrict__ wA,            // f_{n0+K}
    float* __restrict__ wB,            // f_{n0+K-1}
    const float* __restrict__ vel2,
    const int2* __restrict__ thrTab,   // NTILES x NTHR
    const float* __restrict__ srcT,
    int n0)
{
    __shared__ __align__(16) float L0[LROWS * WC];
    __shared__ __align__(16) float L1[LROWS * WC];

    const int tid = threadIdx.x;
    const int blk = blockIdx.x;
    const int b   = blk >> 7;          // batch
    const int tb  = blk & 127;         // tile
    const int gi0 = (tb >> 4) << 6;    // interior origin rows
    const int gj0 = (tb & 15) << 5;    // interior origin cols
    const int bi0 = gi0 - 16;
    const int bj0 = gj0 - 16;

    const int grp = tid >> 4;          // 0..11
    const int r0  = grp << 3;          // own window rows r0..r0+7
    const int c0  = (tid & 15) << 2;   // own window cols
    const int base = (grp + 1) << 2;   // own boundary-slot base

    // ---- zero pad slots (0..3, 52..55) of both buffers ----
    for (int q = tid; q < 256; q += NTHR) {
        int buf = q >= 128;
        int p = q & 127;
        int pr = p >> 4;               // 0..7
        int pc = (p & 15) << 2;
        int slot = (pr < 4) ? pr : (pr + 48);   // 0..3, 52..55
        float* S = buf ? L1 : L0;
        *(float4*)&S[slot * WC + pc] = make_float4(0.f, 0.f, 0.f, 0.f);
    }

    // ---- prologue: own cells of f_{n0}, f_{n0-1}, vel2 ----
    float curR[8][4], prvR[8][4], v2R[8][4];
    const float* gAb = gA + (b << 18);
    const float* gBb = gB + (b << 18);
    const float* gVb = vel2 + (b << 18);
#pragma unroll
    for (int r = 0; r < 8; ++r) {
        int gi = (bi0 + r0 + r) & 511;
        int gj = (bj0 + c0) & 511;
        float4 cv = *(const float4*)&gAb[(gi << 9) | gj];
        float4 pv = *(const float4*)&gBb[(gi << 9) | gj];
        float4 vv = *(const float4*)&gVb[(gi << 9) | gj];
        curR[r][0] = cv.x; curR[r][1] = cv.y; curR[r][2] = cv.z; curR[r][3] = cv.w;
        prvR[r][0] = pv.x; prvR[r][1] = pv.y; prvR[r][2] = pv.z; prvR[r][3] = pv.w;
        v2R[r][0] = vv.x; v2R[r][1] = vv.y; v2R[r][2] = vv.z; v2R[r][3] = vv.w;
    }

    // ---- inj/meas descriptor ----
    const int2 tw = thrTab[tb * NTHR + tid];
    int injCell = -1;  float injV = 0.0f;
    if (tw.x >= 0) { injCell = tw.x & 31; injV = 0.09f * se[tw.x >> 8]; }
    int m1Cell = -1, m1Addr = 0, m2Cell = -1, m2Addr = 0;
    {
        int h1 = tw.y & 0xFFFF, h2 = (tw.y >> 16) & 0xFFFF;
        if (h1 & 0x8000) { m1Cell = (h1 >> 8) & 31; m1Addr = (b << 16) | ((h1 & 255) << 8); }
        if (h2 & 0x8000) { m2Cell = (h2 >> 8) & 31; m2Addr = (b << 16) | ((h2 & 255) << 8); }
    }
    const bool rare = (injCell >= 0) || (m1Cell >= 0) || (m2Cell >= 0);

    // ---- publish f_{n0} boundary rows ----
    *(float4*)&L0[(base + 0) * WC + c0] = make_float4(curR[0][0], curR[0][1], curR[0][2], curR[0][3]);
    *(float4*)&L0[(base + 1) * WC + c0] = make_float4(curR[1][0], curR[1][1], curR[1][2], curR[1][3]);
    *(float4*)&L0[(base + 2) * WC + c0] = make_float4(curR[6][0], curR[6][1], curR[6][2], curR[6][3]);
    *(float4*)&L0[(base + 3) * WC + c0] = make_float4(curR[7][0], curR[7][1], curR[7][2], curR[7][3]);
    __syncthreads();

#pragma unroll 1
    for (int s = 0; s < K; s += 2) {
        float sva = srcT[n0 + s];
        float svb = srcT[n0 + s + 1];

        do_step(L0, L1, v2R, curR, prvR, base, c0);    // prvR <- f_{n+1}
        if (rare) patch_step(prvR, L1, out, base, c0, injCell, injV * sva,
                             m1Cell, m1Addr, m2Cell, m2Addr, n0 + s);
        __syncthreads();

        do_step(L1, L0, v2R, prvR, curR, base, c0);    // curR <- f_{n+2}
        if (rare) patch_step(curR, L0, out, base, c0, injCell, injV * svb,
                             m1Cell, m1Addr, m2Cell, m2Addr, n0 + s + 1);
        if (s + 2 < K) __syncthreads();
    }

    // ---- write back interior: curR = f_{n0+K}, prvR = f_{n0+K-1} ----
    if (r0 >= 16 && r0 < 80 && c0 >= 16 && c0 < 48) {
        int gj = gj0 + (c0 - 16);
#pragma unroll
        for (int r = 0; r < 8; ++r) {
            int gi = gi0 + (r0 - 16) + r;
            *(float4*)&wA[(b << 18) | (gi << 9) | gj] =
                make_float4(curR[r][0], curR[r][1], curR[r][2], curR[r][3]);
            *(float4*)&wB[(b << 18) | (gi << 9) | gj] =
                make_float4(prvR[r][0], prvR[r][1], prvR[r][2], prvR[r][3]);
        }
    }
}

// ---------------------------------------------------------------------------
extern "C" void kernel_launch(void* const* d_in, const int* in_sizes, int n_in,
                              void* d_out, int out_size, void* d_ws, size_t ws_size,
                              hipStream_t stream) {
    const float* x  = (const float*)d_in[0];
    const float* se = (const float*)d_in[1];
    float* out = (float*)d_out;

    float* ws = (float*)d_ws;
    const int FSZ = NB * NPTS;
    float* f[4]  = {ws, ws + FSZ, ws + 2 * FSZ, ws + 3 * FSZ};
    float* dVel  = ws + 4 * FSZ;
    int2*  dTT   = (int2*)(ws + 5 * FSZ);               // 128*192 int2
    float* dSrc  = (float*)(ws + 5 * FSZ + NTILES * NTHR * 2);

    static int   h_tt[NTILES * NTHR * 2];
    static float h_src[NT];
    static int   h_mx[NM], h_my[NM];
    for (int m = 0; m < NM; ++m) {
        double theta = (2.0 * M_PI * (double)m) / 256.0;
        h_mx[m] = (int)(256.0 + 200.0 * cos(theta));
        h_my[m] = (int)(256.0 + 200.0 * sin(theta));
    }
    for (int i = 0; i < NTILES * NTHR; ++i) { h_tt[2*i] = -1; h_tt[2*i+1] = 0; }
    for (int tile = 0; tile < NTILES; ++tile) {
        int bi0 = ((tile >> 4) << 6) - 16;
        int bj0 = ((tile & 15) << 5) - 16;
        for (int m = 0; m < NM; ++m) {
            int d = (h_mx[m] - bi0) & 511;
            int e = (h_my[m] - bj0) & 511;
            if (d >= WR || e >= WC) continue;
            int tidx = (d >> 3) * 16 + (e >> 2);
            int cell = ((d & 7) << 2) | (e & 3);         // 0..31
            int basei = (tile * NTHR + tidx) * 2;
            if ((m & 3) == 0) h_tt[basei] = ((m >> 2) << 8) | cell;
            if (d >= 16 && d < 80 && e >= 16 && e < 48) {
                int pk = 0x8000 | (cell << 8) | m;
                if (!(h_tt[basei + 1] & 0x8000)) h_tt[basei + 1] |= pk;
                else                             h_tt[basei + 1] |= pk << 16;
            }
        }
    }
    for (int t = 0; t < NT; ++t) {
        float tj  = (float)t * 2e-05f;
        float arg = (float)(2.0 * M_PI * 500.0) * tj;
        float d   = tj - 0.002f;
        float e   = -(d * d) / (float)(2.0 * 0.001 * 0.001);
        h_src[t]  = sinf(arg) * expf(e);
    }
    hipMemcpyAsync(dTT,  h_tt,  sizeof(h_tt),  hipMemcpyHostToDevice, stream);
    hipMemcpyAsync(dSrc, h_src, sizeof(h_src), hipMemcpyHostToDevice, stream);

    zero_kernel<<<2048, 256, 0, stream>>>((float4*)ws);
    vel2_kernel<<<NB * NPTS / 256, 256, 0, stream>>>(x, dVel);

    for (int c = 0; c < NCH; ++c) {
        int p = c & 1, q = p ^ 1;
        chunk_kernel<<<NB * NTILES, NTHR, 0, stream>>>(
            se, out,
            f[2 * p], f[2 * p + 1],
            f[2 * q], f[2 * q + 1],
            dVel, dTT, dSrc, c * K);
    }
}

// Round 18
// 670.628 us; speedup vs baseline: 1.4432x; 1.3662x over previous
//
#include <hip/hip_runtime.h>
#include <math.h>
#include <string.h>

#define NXG 512
#define NPTS (NXG * NXG)
#define NB 4
#define NT 256
#define NM 256
#define K 16                // steps per chunk
#define NCH (NT / K)        // 16 chunks
#define WROWS 128           // window rows (64 interior + 2*32 halo)
#define WCOLS 128           // window cols
#define NTHR 512            // 16 row-groups x 32 cols; 8x4 cells per thread
#define NTILES 64           // 8x8 tiles (64x64 interior)
#define LROWS 72            // LDS slots: (16+2 pad) groups x 4 rows

// DPP wave shifts (lane+-1). Cross-thread junk lands only in column-halo
// threads (col 0 / 31) — garbage-tolerant by the 32-wide halo argument.
__device__ __forceinline__ float dpp_left(float v) {
    return __int_as_float(__builtin_amdgcn_mov_dpp(__float_as_int(v),
                                                   0x138, 0xf, 0xf, true));
}
__device__ __forceinline__ float dpp_right(float v) {
    return __int_as_float(__builtin_amdgcn_mov_dpp(__float_as_int(v),
                                                   0x130, 0xf, 0xf, true));
}

// ---------------------------------------------------------------------------
// One row: reads cur rows + old dst[r] (previous field), writes the new
// field IN PLACE into dst[r]. No inj/meas code in the hot path.
// ---------------------------------------------------------------------------
__device__ __forceinline__ void row_calc(
    const float (&cur)[8][4], float (&dst)[8][4],
    const float (&v2R)[8][4], int r,
    const float* __restrict__ xm2, const float* __restrict__ xm1,
    const float* __restrict__ xp1, const float* __restrict__ xp2)
{
    float y[8] = {dpp_left(cur[r][2]), dpp_left(cur[r][3]),
                  cur[r][0], cur[r][1], cur[r][2], cur[r][3],
                  dpp_right(cur[r][0]), dpp_right(cur[r][1])};
#pragma unroll
    for (int c = 0; c < 4; ++c) {
        float cc = cur[r][c];
        float sum1 = (xm1[c] + xp1[c]) + (y[c + 1] + y[c + 3]);
        float sum2 = (xm2[c] + xp2[c]) + (y[c] + y[c + 4]);
        float w = fmaf(-60.0f, cc, fmaf(16.0f, sum1, -sum2));
        dst[r][c] = fmaf(v2R[r][c], w, fmaf(2.0f, cc, -dst[r][c]));
    }
}

// ---------------------------------------------------------------------------
__device__ __forceinline__ void do_step(
    const float* __restrict__ Lc, float* __restrict__ Ln,
    const float (&v2R)[8][4], float (&cur)[8][4], float (&nw)[8][4],
    int base, int c0)
{
    float4 a4 = *(const float4*)&Lc[(base - 2) * WCOLS + c0];  // row r0-2
    float4 b4 = *(const float4*)&Lc[(base - 1) * WCOLS + c0];  // row r0-1
    float4 c4 = *(const float4*)&Lc[(base + 4) * WCOLS + c0];  // row r0+8
    float4 d4 = *(const float4*)&Lc[(base + 5) * WCOLS + c0];  // row r0+9

#pragma unroll
    for (int r = 2; r < 6; ++r)
        row_calc(cur, nw, v2R, r, cur[r - 2], cur[r - 1], cur[r + 1], cur[r + 2]);

    float ha[4] = {a4.x, a4.y, a4.z, a4.w};
    float hb[4] = {b4.x, b4.y, b4.z, b4.w};
    row_calc(cur, nw, v2R, 0, ha, hb, cur[1], cur[2]);
    *(float4*)&Ln[(base + 0) * WCOLS + c0] =
        make_float4(nw[0][0], nw[0][1], nw[0][2], nw[0][3]);
    row_calc(cur, nw, v2R, 1, hb, cur[0], cur[2], cur[3]);
    *(float4*)&Ln[(base + 1) * WCOLS + c0] =
        make_float4(nw[1][0], nw[1][1], nw[1][2], nw[1][3]);

    float hc[4] = {c4.x, c4.y, c4.z, c4.w};
    float hd[4] = {d4.x, d4.y, d4.z, d4.w};
    row_calc(cur, nw, v2R, 6, cur[4], cur[5], cur[7], hc);
    *(float4*)&Ln[(base + 2) * WCOLS + c0] =
        make_float4(nw[6][0], nw[6][1], nw[6][2], nw[6][3]);
    row_calc(cur, nw, v2R, 7, cur[5], cur[6], hc, hd);
    *(float4*)&Ln[(base + 3) * WCOLS + c0] =
        make_float4(nw[7][0], nw[7][1], nw[7][2], nw[7][3]);
}

// ---------------------------------------------------------------------------
// Rare post-step patch: injection add (+ LDS boundary refresh), then
// measurement reads of the PATCHED new field.
// ---------------------------------------------------------------------------
__device__ __forceinline__ void patch_step(
    float (&f)[8][4], float* __restrict__ Ln, float* __restrict__ out,
    int base, int c0, int injCell, float addv,
    int m1Cell, int m1Addr, int m2Cell, int m2Addr, int n)
{
    if (injCell >= 0) {
#pragma unroll
        for (int r = 0; r < 8; ++r)
#pragma unroll
            for (int c = 0; c < 4; ++c)
                if (((r << 2) | c) == injCell) f[r][c] += addv;
        int ir = injCell >> 2;
        if (ir == 0) *(float4*)&Ln[(base + 0) * WCOLS + c0] = make_float4(f[0][0], f[0][1], f[0][2], f[0][3]);
        if (ir == 1) *(float4*)&Ln[(base + 1) * WCOLS + c0] = make_float4(f[1][0], f[1][1], f[1][2], f[1][3]);
        if (ir == 6) *(float4*)&Ln[(base + 2) * WCOLS + c0] = make_float4(f[6][0], f[6][1], f[6][2], f[6][3]);
        if (ir == 7) *(float4*)&Ln[(base + 3) * WCOLS + c0] = make_float4(f[7][0], f[7][1], f[7][2], f[7][3]);
    }
    if (m1Cell >= 0) {
        float v = 0.0f;
#pragma unroll
        for (int r = 0; r < 8; ++r)
#pragma unroll
            for (int c = 0; c < 4; ++c)
                if (((r << 2) | c) == m1Cell) v = f[r][c];
        out[m1Addr | n] = v;
    }
    if (m2Cell >= 0) {
        float v = 0.0f;
#pragma unroll
        for (int r = 0; r < 8; ++r)
#pragma unroll
            for (int c = 0; c < 4; ++c)
                if (((r << 2) | c) == m2Cell) v = f[r][c];
        out[m2Addr | n] = v;
    }
}

// ---------------------------------------------------------------------------
__global__ __launch_bounds__(NTHR, 2) void chunk_kernel(
    const float* __restrict__ x,       // (4,1,256,256) — used by chunk 0 only
    const float* __restrict__ se,      // (64,)
    float* __restrict__ out,           // (4,1,256,256) = [b][m][t]
    const float* __restrict__ gA,      // f_{n0}   (unused when n0==0: zeros)
    const float* __restrict__ gB,      // f_{n0-1} (unused when n0==0)
    float* __restrict__ wA,            // f_{n0+K}
    float* __restrict__ wB,            // f_{n0+K-1}
    float* __restrict__ vel2,          // v2/12 table: written by chunk 0,
                                       // read by chunks 1+
    const int2* __restrict__ thrTab,   // NTILES x NTHR
    const float* __restrict__ srcT,
    int n0)
{
    __shared__ __align__(16) float L0[LROWS * WCOLS];
    __shared__ __align__(16) float L1[LROWS * WCOLS];

    const int tid = threadIdx.x;
    const int blk = blockIdx.x;
    const int b   = blk >> 6;          // batch
    const int tb  = blk & 63;          // tile
    const int gi0 = (tb >> 3) << 6;
    const int gj0 = (tb & 7) << 6;
    const int bi0 = gi0 - 32;
    const int bj0 = gj0 - 32;

    const int grp = tid >> 5;          // 0..15
    const int r0  = grp << 3;          // own window rows r0..r0+7
    const int c0  = (tid & 31) << 2;   // own window cols
    const int base = (grp + 1) << 2;   // LDS slot base

    const bool wbT = (r0 >= 32 && r0 < 96 && c0 >= 32 && c0 < 96);

    // ---- prologue ----
    float curR[8][4], prvR[8][4], v2R[8][4];
    if (n0 == 0) {
        // fields start at zero; compute vel2 in registers (once per run) and
        // have interior threads persist the table for chunks 1..15
#pragma unroll
        for (int r = 0; r < 8; ++r) {
            int gi = (bi0 + r0 + r) & 511;
            int gjb = (bj0 + c0) & 511;
#pragma unroll
            for (int c = 0; c < 4; ++c) {
                int gj = gjb + c;
                float v;
                if (gi < 55 || gi >= 457 || gj < 55 || gj >= 457) v = 1e-6f;
                else if (gi >= 128 && gi < 384 && gj >= 128 && gj < 384)
                    v = x[(b << 16) | ((gi - 128) << 8) | (gj - 128)];
                else v = 1.5f;
                float a = (2e-05f * v) / 1e-04f;
                v2R[r][c] = a * a * (1.0f / 12.0f);
                curR[r][c] = 0.0f;
                prvR[r][c] = 0.0f;
            }
        }
        if (wbT) {
            int gj = gj0 + (c0 - 32);
#pragma unroll
            for (int r = 0; r < 8; ++r) {
                int gi = gi0 + (r0 - 32) + r;
                *(float4*)&vel2[(b << 18) | (gi << 9) | gj] =
                    make_float4(v2R[r][0], v2R[r][1], v2R[r][2], v2R[r][3]);
            }
        }
    } else {
        const float* gAb = gA + (b << 18);
        const float* gBb = gB + (b << 18);
        const float* gVb = vel2 + (b << 18);
#pragma unroll
        for (int r = 0; r < 8; ++r) {
            int gi = (bi0 + r0 + r) & 511;
            int gj = (bj0 + c0) & 511;
            float4 cv = *(const float4*)&gAb[(gi << 9) | gj];
            float4 pv = *(const float4*)&gBb[(gi << 9) | gj];
            float4 vv = *(const float4*)&gVb[(gi << 9) | gj];
            curR[r][0] = cv.x; curR[r][1] = cv.y; curR[r][2] = cv.z; curR[r][3] = cv.w;
            prvR[r][0] = pv.x; prvR[r][1] = pv.y; prvR[r][2] = pv.z; prvR[r][3] = pv.w;
            v2R[r][0] = vv.x; v2R[r][1] = vv.y; v2R[r][2] = vv.z; v2R[r][3] = vv.w;
        }
    }

    // ---- inj/meas descriptor ----
    const int2 tw = thrTab[(tb << 9) | tid];
    int injCell = -1;  float injV = 0.0f;
    if (tw.x >= 0) { injCell = tw.x & 31; injV = 0.09f * se[tw.x >> 8]; }
    int m1Cell = -1, m1Addr = 0, m2Cell = -1, m2Addr = 0;
    {
        int h1 = tw.y & 0xFFFF, h2 = (tw.y >> 16) & 0xFFFF;
        if (h1 & 0x8000) { m1Cell = (h1 >> 8) & 31; m1Addr = (b << 16) | ((h1 & 255) << 8); }
        if (h2 & 0x8000) { m2Cell = (h2 >> 8) & 31; m2Addr = (b << 16) | ((h2 & 255) << 8); }
    }
    const bool rare = (injCell >= 0) || (m1Cell >= 0) || (m2Cell >= 0);

    // ---- publish f_{n0} boundary rows ----
    *(float4*)&L0[(base + 0) * WCOLS + c0] = make_float4(curR[0][0], curR[0][1], curR[0][2], curR[0][3]);
    *(float4*)&L0[(base + 1) * WCOLS + c0] = make_float4(curR[1][0], curR[1][1], curR[1][2], curR[1][3]);
    *(float4*)&L0[(base + 2) * WCOLS + c0] = make_float4(curR[6][0], curR[6][1], curR[6][2], curR[6][3]);
    *(float4*)&L0[(base + 3) * WCOLS + c0] = make_float4(curR[7][0], curR[7][1], curR[7][2], curR[7][3]);
    __syncthreads();

#pragma unroll 1
    for (int s = 0; s < K; s += 2) {    // 2 steps/iter — body fits I-cache
        float sva = srcT[n0 + s];
        float svb = srcT[n0 + s + 1];

        do_step(L0, L1, v2R, curR, prvR, base, c0);    // prvR <- f_{n+1}
        if (rare) patch_step(prvR, L1, out, base, c0, injCell, injV * sva,
                             m1Cell, m1Addr, m2Cell, m2Addr, n0 + s);
        __syncthreads();

        do_step(L1, L0, v2R, prvR, curR, base, c0);    // curR <- f_{n+2}
        if (rare) patch_step(curR, L0, out, base, c0, injCell, injV * svb,
                             m1Cell, m1Addr, m2Cell, m2Addr, n0 + s + 1);
        if (s + 2 < K) __syncthreads();
    }

    // ---- write back interior: curR = f_{n0+K}, prvR = f_{n0+K-1} ----
    if (wbT) {
        int gj = gj0 + (c0 - 32);
#pragma unroll
        for (int r = 0; r < 8; ++r) {
            int gi = gi0 + (r0 - 32) + r;
            *(float4*)&wA[(b << 18) | (gi << 9) | gj] =
                make_float4(curR[r][0], curR[r][1], curR[r][2], curR[r][3]);
            *(float4*)&wB[(b << 18) | (gi << 9) | gj] =
                make_float4(prvR[r][0], prvR[r][1], prvR[r][2], prvR[r][3]);
        }
    }
}

// ---------------------------------------------------------------------------
extern "C" void kernel_launch(void* const* d_in, const int* in_sizes, int n_in,
                              void* d_out, int out_size, void* d_ws, size_t ws_size,
                              hipStream_t stream) {
    const float* x  = (const float*)d_in[0];
    const float* se = (const float*)d_in[1];
    float* out = (float*)d_out;

    float* ws = (float*)d_ws;
    const int FSZ = NB * NPTS;                 // 4 MB per field (floats)
    float* f[4]  = {ws, ws + FSZ, ws + 2 * FSZ, ws + 3 * FSZ};
    float* dVel  = ws + 4 * FSZ;                        // 4 MB, written chunk 0
    int*   dBlob = (int*)(ws + 5 * FSZ);
    int2*  dTT   = (int2*)dBlob;                        // 64*512 int2
    float* dSrc  = (float*)(dBlob + NTILES * NTHR * 2);

    // ---- host tables, single blob, single H2D copy ----
    static int h_blob[NTILES * NTHR * 2 + NT];
    int*   h_tt  = h_blob;
    static float h_src[NT];
    static int h_mx[NM], h_my[NM];
    for (int m = 0; m < NM; ++m) {
        double theta = (2.0 * M_PI * (double)m) / 256.0;
        h_mx[m] = (int)(256.0 + 200.0 * cos(theta));
        h_my[m] = (int)(256.0 + 200.0 * sin(theta));
    }
    for (int i = 0; i < NTILES * NTHR; ++i) { h_tt[2*i] = -1; h_tt[2*i+1] = 0; }
    for (int tile = 0; tile < NTILES; ++tile) {
        int bi0 = ((tile >> 3) << 6) - 32;
        int bj0 = ((tile & 7) << 6) - 32;
        for (int m = 0; m < NM; ++m) {
            int d = (h_mx[m] - bi0) & 511;
            int e = (h_my[m] - bj0) & 511;
            if (d >= WROWS || e >= WCOLS) continue;
            int tidx = (d >> 3) * 32 + (e >> 2);
            int cell = ((d & 7) << 2) | (e & 3);         // 0..31
            int basei = (tile * NTHR + tidx) * 2;
            if ((m & 3) == 0) h_tt[basei] = ((m >> 2) << 8) | cell;
            if (d >= 32 && d < 96 && e >= 32 && e < 96) {
                int pk = 0x8000 | (cell << 8) | m;
                if (!(h_tt[basei + 1] & 0x8000)) h_tt[basei + 1] |= pk;
                else                             h_tt[basei + 1] |= pk << 16;
            }
        }
    }
    for (int t = 0; t < NT; ++t) {
        float tj  = (float)t * 2e-05f;
        float arg = (float)(2.0 * M_PI * 500.0) * tj;
        float d   = tj - 0.002f;
        float e   = -(d * d) / (float)(2.0 * 0.001 * 0.001);
        h_src[t]  = sinf(arg) * expf(e);
    }
    memcpy(&h_blob[NTILES * NTHR * 2], h_src, sizeof(h_src));
    hipMemcpyAsync(dBlob, h_blob, sizeof(h_blob), hipMemcpyHostToDevice, stream);

    for (int c = 0; c < NCH; ++c) {
        int p = c & 1, q = p ^ 1;
        chunk_kernel<<<NB * NTILES, NTHR, 0, stream>>>(
            x, se, out,
            f[2 * p], f[2 * p + 1],     // unused when c==0 (fields are zero)
            f[2 * q], f[2 * q + 1],
            dVel, dTT, dSrc, c * K);
    }
}